// Round 8
// baseline (169.704 us; speedup 1.0000x reference)
//
#include <hip/hip_runtime.h>

#define DIM           1024
#define BLK           64
#define NB            16      // DIM/BLK
#define RT            16      // rows per tile
#define MAIN_THREADS  512     // 8 waves; wave w owns blocks w and w+8
#define NWG           512     // 2 WGs per CU
#define TPW           8       // tiles per WG (4096 / 512)
#define P68           68      // padded LDS row for expm
#define BFRAG_STRIDE  512     // ushorts per (k,n0,h) B-frag block
#define GSTRIDE       272     // LDS bytes per 4-col group (64 data + 16 pad)

typedef float  f32x4  __attribute__((ext_vector_type(4)));
typedef int    i32x4  __attribute__((ext_vector_type(4)));
typedef short  bf16x8 __attribute__((ext_vector_type(8)));

// f32 -> bf16 bits, round-to-nearest-even (for expm output)
static __device__ __forceinline__ short f2bf(float f) {
    union { float f; unsigned u; } v; v.f = f;
    unsigned r = v.u + 0x7fffu + ((v.u >> 16) & 1u);
    return (short)(r >> 16);
}

// packed f32x2 -> bf16x2 (single VALU op)
static __device__ __forceinline__ unsigned cvt_pk(float lo, float hi) {
    unsigned r;
    asm("v_cvt_pk_bf16_f32 %0, %1, %2" : "=v"(r) : "v"(lo), "v"(hi));
    return r;
}

#define WAITL()   asm volatile("s_waitcnt lgkmcnt(0)" ::: "memory")
#define SBAR()    __builtin_amdgcn_s_barrier()

// ---------------------------------------------------------------------------
// Kernel 1 (fused): blocks 0..15 = per-block expm (Taylor to A^7/7!);
// block 16 = perm decode -> INVERSE permutation pinv (pinv[perm[j]] = j).
// Btl[((k*4+n)*2+h)*512 + g*128 + m*8 + j] = B_k[h*32+g*8+j][n*16+m], bf16.
// ---------------------------------------------------------------------------
__global__ __launch_bounds__(512) void expm_kernel(
        const float* __restrict__ skew, ushort* __restrict__ Btl,
        const int* __restrict__ praw, int* __restrict__ pinv) {
    __shared__ float Asm[BLK][P68];
    __shared__ float Tb[2][BLK][P68];
    __shared__ float Rm[BLK][P68];
    const int tid = threadIdx.x;

    if (blockIdx.x == NB) {                 // ---- perm decode -> inverse ----
        __shared__ int zc;
        if (tid == 0) zc = 0;
        __syncthreads();
        int local = 0;
        for (int i = tid; i < DIM; i += 512)
            if (praw[i] == 0) local++;
        if (local) atomicAdd(&zc, local);
        __syncthreads();
        const bool is64 = (zc > 100);       // i64 read as i32: ~512 zero hi-words
        const long long* p64 = (const long long*)praw;
        for (int i = tid; i < DIM; i += 512) {
            const int v = is64 ? (int)p64[i] : praw[i];
            pinv[v] = i;
        }
        return;
    }

    const int k = blockIdx.x;
    const float* P = skew + (size_t)k * (BLK * BLK);

    for (int e = tid; e < BLK * BLK; e += 512) {
        const int i = e >> 6, j = e & 63;
        const float a = P[i * BLK + j] - P[j * BLK + i];   // A = P - P^T
        Asm[i][j]   = a;
        Tb[0][i][j] = a;                                   // T_1 = A
        Rm[i][j]    = a + (i == j ? 1.0f : 0.0f);          // R = I + A
    }
    __syncthreads();

    const int i0 = (tid >> 4) * 2;
    const int j0 = (tid & 15) * 4;

    for (int n = 2; n <= 7; ++n) {   // T_n = T_{n-1} * A / n ; R += T_n
        const float invn = 1.0f / (float)n;
        const float (*Tc)[P68] = Tb[n & 1];
        float       (*Tn)[P68] = Tb[1 - (n & 1)];
        f32x4 acc0 = {0.f, 0.f, 0.f, 0.f}, acc1 = {0.f, 0.f, 0.f, 0.f};
        for (int b = 0; b < BLK; ++b) {
            const f32x4 av = *(const f32x4*)&Asm[b][j0];
            acc0 += Tc[i0][b]     * av;
            acc1 += Tc[i0 + 1][b] * av;
        }
        acc0 *= invn; acc1 *= invn;
        *(f32x4*)&Tn[i0][j0]     = acc0;
        *(f32x4*)&Tn[i0 + 1][j0] = acc1;
        f32x4 r0 = *(const f32x4*)&Rm[i0][j0];     r0 += acc0; *(f32x4*)&Rm[i0][j0]     = r0;
        f32x4 r1 = *(const f32x4*)&Rm[i0 + 1][j0]; r1 += acc1; *(f32x4*)&Rm[i0 + 1][j0] = r1;
        __syncthreads();
    }

    for (int e = tid; e < BLK * BLK; e += 512) {
        const int b = e >> 6, c = e & 63;        // value B[b][c]
        const int n = c >> 4, m = c & 15;
        const int h = b >> 5, g = (b >> 3) & 3, j = b & 7;
        const size_t idx = (size_t)((k * 4 + n) * 2 + h) * BFRAG_STRIDE
                         + g * 128 + m * 8 + j;
        Btl[idx] = (ushort)f2bf(Rm[b][c]);
    }
}

// ---------------------------------------------------------------------------
// Kernel 2: persistent main, 2 WGs/CU for TLP (VGPR-safe: no reg prefetch).
// 512 WGs x 8 tiles; 512 threads = 8 waves; wave w owns blocks w, w+8 and
// epilogue rows w, w+8. Per tile (2 barriers, no vmcnt drains):
//   per block b in {w, w+8}: load A (16 regs, at-use) -> cvt_pk -> 8x MFMA
//     -> scatter 16 ds_write_b32 into pre-permuted y'
//   WAITL+SBAR; epilogue (conflict-free b128 reads + coalesced stores);
//   WAITL+SBAR.
// Exposed load latency per block is covered by the co-resident second WG.
// LDS y' layout: addr(row, j) = (j>>2)*272 + (((row + 2*(j>>2)) & 15)<<4)
//   + (j&3)*4.  272B group stride + additive slot rotation -> epilogue b128
//   start-bank = 4*((3*g4 + r) mod 8): full 8-phase rotation, conflict-free;
//   scatter (random g4 per lane) ~uniform over 32 banks.
// VGPR budget: bfr 64 + a-load 16 + cvt 8 + acc 16 + pk 8 + misc ~15 <= 128.
// ---------------------------------------------------------------------------
__global__ __launch_bounds__(MAIN_THREADS, 4) void gsl_main_kernel(
        const float* __restrict__ x, const ushort* __restrict__ Btl,
        const int* __restrict__ pinv, float* __restrict__ out) {
    __shared__ float ybuf[256 * GSTRIDE / 4];   // 68 KB permuted-y tile

    const int tid  = threadIdx.x;
    const int lane = tid & 63;
    const int w    = tid >> 6;         // wave 0..7
    const int g    = lane >> 4;        // 0..3
    const int m16  = lane & 15;

    // B-frags for blocks w, w+8: 16 x bf16x8 = 64 VGPR (persistent)
    bf16x8 bfr[2][4][2];
#pragma unroll
    for (int b = 0; b < 2; ++b) {
        const int k = w + 8 * b;
#pragma unroll
        for (int n = 0; n < 4; ++n)
#pragma unroll
            for (int h = 0; h < 2; ++h)
                bfr[b][n][h] = *(const bf16x8*)(Btl +
                    (size_t)((k * 4 + n) * 2 + h) * BFRAG_STRIDE + lane * 8);
    }

    // Packed scatter bases: for col c = (w+8b)*64+n*16+m16, j = pinv[c]:
    // pk = [g4*272 + (j&3)*4] | (((4g + 2*g4)&15) << 20)
    // write addr(i) = (pk & 0xFFFFF) + ((((pk>>20) + i) & 15) << 4)
    int pk[2][4];
#pragma unroll
    for (int b = 0; b < 2; ++b)
#pragma unroll
        for (int n = 0; n < 4; ++n) {
            const int c  = (w + 8 * b) * 64 + n * 16 + m16;
            const int j  = pinv[c];
            const int g4 = j >> 2;
            pk[b][n] = (g4 * GSTRIDE + (j & 3) * 4)
                     | (((4 * g + 2 * g4) & 15) << 20);
        }

    const int   tile0 = blockIdx.x * TPW;
    char* const yB    = (char*)ybuf;

    for (int it = 0; it < TPW; ++it) {
        const size_t rbase = (size_t)(tile0 + it) * RT;

#pragma unroll
        for (int b = 0; b < 2; ++b) {
            // A-load at use (16 VGPR): rows m16, block (w + 8b), seg g
            const float* xp = x + (rbase + m16) * DIM + w * 64 + b * 512 + g * 8;
            const f32x4 a0 = *(const f32x4*)(xp);
            const f32x4 a1 = *(const f32x4*)(xp + 4);
            const f32x4 a2 = *(const f32x4*)(xp + 32);
            const f32x4 a3 = *(const f32x4*)(xp + 36);

            i32x4 plo, phi;
            plo[0] = cvt_pk(a0[0], a0[1]); plo[1] = cvt_pk(a0[2], a0[3]);
            plo[2] = cvt_pk(a1[0], a1[1]); plo[3] = cvt_pk(a1[2], a1[3]);
            phi[0] = cvt_pk(a2[0], a2[1]); phi[1] = cvt_pk(a2[2], a2[3]);
            phi[2] = cvt_pk(a3[0], a3[1]); phi[3] = cvt_pk(a3[2], a3[3]);
            const bf16x8 alo = __builtin_bit_cast(bf16x8, plo);
            const bf16x8 ahi = __builtin_bit_cast(bf16x8, phi);

            f32x4 acc[4];
#pragma unroll
            for (int n = 0; n < 4; ++n) acc[n] = (f32x4){0.f, 0.f, 0.f, 0.f};
#pragma unroll
            for (int n = 0; n < 4; ++n)
                acc[n] = __builtin_amdgcn_mfma_f32_16x16x32_bf16(alo, bfr[b][n][0], acc[n], 0, 0, 0);
#pragma unroll
            for (int n = 0; n < 4; ++n)
                acc[n] = __builtin_amdgcn_mfma_f32_16x16x32_bf16(ahi, bfr[b][n][1], acc[n], 0, 0, 0);

#pragma unroll
            for (int n = 0; n < 4; ++n) {
                const int base = pk[b][n] & 0xFFFFF;
                const int rot  = pk[b][n] >> 20;
#pragma unroll
                for (int i = 0; i < 4; ++i)
                    *(float*)(yB + base + (((rot + i) & 15) << 4)) = acc[n][i];
            }
        }

        WAITL(); SBAR();               // all scatters visible

        // ---- epilogue: rows w and w+8, conflict-free reads, coalesced stores
#pragma unroll
        for (int rr = 0; rr < 2; ++rr) {
            const int r = w + 8 * rr;
            float* orow = out + (rbase + r) * DIM;
#pragma unroll
            for (int i2 = 0; i2 < 4; ++i2) {
                const int q = lane + 64 * i2;
                const f32x4 v = *(const f32x4*)(yB + q * GSTRIDE +
                                                (((r + 2 * q) & 15) << 4));
                *(f32x4*)(orow + q * 4) = v;
            }
        }

        WAITL(); SBAR();               // epilogue reads done before next scatter
    }
}

// ---------------------------------------------------------------------------
extern "C" void kernel_launch(void* const* d_in, const int* in_sizes, int n_in,
                              void* d_out, int out_size, void* d_ws, size_t ws_size,
                              hipStream_t stream) {
    const float* x    = (const float*)d_in[0];   // [65536, 1024] f32
    const float* skew = (const float*)d_in[1];   // [16, 64, 64] f32
    const int*   perm = (const int*)d_in[2];     // [1024] i32/i64 (detected)
    float* out = (float*)d_out;

    // ws: [0,128KB) Btl bf16 lane-linear; [128KB,+4KB) inverse perm i32
    ushort* Btl  = (ushort*)d_ws;
    int*    pinv = (int*)((char*)d_ws + (size_t)NB * BLK * BLK * sizeof(ushort));

    expm_kernel<<<NB + 1, 512, 0, stream>>>(skew, Btl, perm, pinv);
    gsl_main_kernel<<<NWG, MAIN_THREADS, 0, stream>>>(x, Btl, pinv, out);
}

// Round 9
// 132.158 us; speedup vs baseline: 1.2841x; 1.2841x over previous
//
#include <hip/hip_runtime.h>

#define DIM           1024
#define BLK           64
#define NB            16      // DIM/BLK
#define RT            16      // rows per tile
#define MAIN_THREADS  1024    // 16 waves; wave w owns block w and row w
#define NWG           256     // persistent
#define TPW           16      // tiles per WG (4096 / 256)
#define P68           68      // padded LDS row for expm
#define BFRAG_STRIDE  512     // ushorts per (k,n0,h) B-frag block

typedef float  f32x4  __attribute__((ext_vector_type(4)));
typedef unsigned uintx2 __attribute__((ext_vector_type(2)));
typedef short  bf16x8 __attribute__((ext_vector_type(8)));

// f32 -> bf16 bits, round-to-nearest-even
static __device__ __forceinline__ ushort f2bf(float f) {
    union { float f; unsigned u; } v; v.f = f;
    unsigned r = v.u + 0x7fffu + ((v.u >> 16) & 1u);
    return (ushort)(r >> 16);
}
static __device__ __forceinline__ float bfhi2f(unsigned hi_bits) {  // hi 16 bits
    union { unsigned u; float f; } v; v.u = hi_bits & 0xffff0000u; return v.f;
}
static __device__ __forceinline__ float bflo2f(unsigned lo_bits) {  // lo 16 bits
    union { unsigned u; float f; } v; v.u = lo_bits << 16; return v.f;
}

#define WAITL()   asm volatile("s_waitcnt lgkmcnt(0)" ::: "memory")
#define SBAR()    __builtin_amdgcn_s_barrier()

// ---------------------------------------------------------------------------
// Kernel 1 (fused): blocks 0..15 = per-block expm (Taylor to A^7/7!);
// block 16 = perm decode -> INVERSE permutation pinv (pinv[perm[j]] = j).
// Btl[((k*4+n)*2+h)*512 + g*128 + m*8 + j] = B_k[h*32+g*8+j][n*16+m], bf16.
// ---------------------------------------------------------------------------
__global__ __launch_bounds__(512) void expm_kernel(
        const float* __restrict__ skew, ushort* __restrict__ Btl,
        const int* __restrict__ praw, int* __restrict__ pinv) {
    __shared__ float Asm[BLK][P68];
    __shared__ float Tb[2][BLK][P68];
    __shared__ float Rm[BLK][P68];
    const int tid = threadIdx.x;

    if (blockIdx.x == NB) {                 // ---- perm decode -> inverse ----
        __shared__ int zc;
        if (tid == 0) zc = 0;
        __syncthreads();
        int local = 0;
        for (int i = tid; i < DIM; i += 512)
            if (praw[i] == 0) local++;
        if (local) atomicAdd(&zc, local);
        __syncthreads();
        const bool is64 = (zc > 100);       // i64 read as i32: ~512 zero hi-words
        const long long* p64 = (const long long*)praw;
        for (int i = tid; i < DIM; i += 512) {
            const int v = is64 ? (int)p64[i] : praw[i];
            pinv[v] = i;
        }
        return;
    }

    const int k = blockIdx.x;
    const float* P = skew + (size_t)k * (BLK * BLK);

    for (int e = tid; e < BLK * BLK; e += 512) {
        const int i = e >> 6, j = e & 63;
        const float a = P[i * BLK + j] - P[j * BLK + i];   // A = P - P^T
        Asm[i][j]   = a;
        Tb[0][i][j] = a;                                   // T_1 = A
        Rm[i][j]    = a + (i == j ? 1.0f : 0.0f);          // R = I + A
    }
    __syncthreads();

    const int i0 = (tid >> 4) * 2;
    const int j0 = (tid & 15) * 4;

    for (int n = 2; n <= 7; ++n) {   // T_n = T_{n-1} * A / n ; R += T_n
        const float invn = 1.0f / (float)n;
        const float (*Tc)[P68] = Tb[n & 1];
        float       (*Tn)[P68] = Tb[1 - (n & 1)];
        f32x4 acc0 = {0.f, 0.f, 0.f, 0.f}, acc1 = {0.f, 0.f, 0.f, 0.f};
        for (int b = 0; b < BLK; ++b) {
            const f32x4 av = *(const f32x4*)&Asm[b][j0];
            acc0 += Tc[i0][b]     * av;
            acc1 += Tc[i0 + 1][b] * av;
        }
        acc0 *= invn; acc1 *= invn;
        *(f32x4*)&Tn[i0][j0]     = acc0;
        *(f32x4*)&Tn[i0 + 1][j0] = acc1;
        f32x4 r0 = *(const f32x4*)&Rm[i0][j0];     r0 += acc0; *(f32x4*)&Rm[i0][j0]     = r0;
        f32x4 r1 = *(const f32x4*)&Rm[i0 + 1][j0]; r1 += acc1; *(f32x4*)&Rm[i0 + 1][j0] = r1;
        __syncthreads();
    }

    for (int e = tid; e < BLK * BLK; e += 512) {
        const int b = e >> 6, c = e & 63;        // value B[b][c]
        const int n = c >> 4, m = c & 15;
        const int h = b >> 5, g = (b >> 3) & 3, j = b & 7;
        const size_t idx = (size_t)((k * 4 + n) * 2 + h) * BFRAG_STRIDE
                         + g * 128 + m * 8 + j;
        Btl[idx] = (ushort)f2bf(Rm[b][c]);
    }
}

// ---------------------------------------------------------------------------
// Kernel 2: persistent main (R6 champion structure + bf16 y' + clean stores).
// 256 WGs x 16 tiles; 1024 threads = 16 waves; wave w owns block w and
// output row w of each tile. Per tile (ONE barrier, no vmcnt drains):
//   - A-frags: direct global->reg f32x4 (prefetched 1 tile ahead, regs
//     freed by bf16 conversion before the prefetch reuses them)
//   - 8x mfma_f32_16x16x32_bf16; acc[n][i] = y[4g+i][w*64+n*16+m16]
//   - scatter acc as BF16 into pre-permuted y' (16x ds_write_b16):
//     byte(row, j) = row*2048 + pinv-col*2; banks ~2-way (random j)
//   - epilogue(it-1) from other y' buffer: b64 reads + shift-convert +
//     f32x4 stores in 2x512B SEGMENTS per instruction (lanes 0-31 ->
//     cols [i*128,+128), lanes 32-63 -> cols [512+i*128,+128)).
//     R2/R4 used <=512B store segments and showed EXACT WRITE_SIZE;
//     R7/R8's 1024B single-segment stores showed 1.41x amplification.
// LDS: 2 x 32KB bf16 y' buffers = 64 KB -> y'-traffic halved vs f32.
// Numerics: y bf16 rounding adds ~0.02 absmax on top of 0.031 (<<0.111).
// ---------------------------------------------------------------------------
__global__ __launch_bounds__(MAIN_THREADS) void gsl_main_kernel(
        const float* __restrict__ x, const ushort* __restrict__ Btl,
        const int* __restrict__ pinv, float* __restrict__ out) {
    __shared__ ushort ybuf[2][RT * DIM];   // 2 x 32 KB bf16 permuted-y tiles

    const int tid  = threadIdx.x;
    const int lane = tid & 63;
    const int w    = tid >> 6;         // wave 0..15 = block id & epilogue row
    const int g    = lane >> 4;        // 0..3
    const int m16  = lane & 15;

    // B-frags for block w: 8 x bf16x8 = 32 regs (persistent)
    bf16x8 bfr[4][2];
#pragma unroll
    for (int n = 0; n < 4; ++n)
#pragma unroll
        for (int h = 0; h < 2; ++h)
            bfr[n][h] = *(const bf16x8*)(Btl +
                (size_t)((w * 4 + n) * 2 + h) * BFRAG_STRIDE + lane * 8);

    // Permuted scatter columns: j = pinv[w*64 + n*16 + m16]
    int jb[4];
#pragma unroll
    for (int n = 0; n < 4; ++n)
        jb[n] = pinv[w * 64 + n * 16 + m16] * 2;   // byte offset within row

    const int tile0 = blockIdx.x * TPW;
    const float* xw = x + w * 64 + g * 8;          // + row*1024 per tile

    // epilogue lane geometry: row w; 2x512B segments per store instruction
    const int hl   = lane >> 5;        // column half 0/1
    const int q32  = lane & 31;
    const int ebase = hl * 512 + q32 * 4;          // element offset in row

    // A(tile0) prefetch
    f32x4 a0, a1, a2, a3;
    {
        const float* xp = xw + (size_t)(tile0 * RT + m16) * DIM;
        a0 = *(const f32x4*)(xp);      a1 = *(const f32x4*)(xp + 4);
        a2 = *(const f32x4*)(xp + 32); a3 = *(const f32x4*)(xp + 36);
    }

    for (int it = 0; it < TPW; ++it) {
        char* const yc = (char*)ybuf[it & 1];

        // convert A(it) -> bf16 (frees a0..a3 for the prefetch)
        bf16x8 alo, ahi;
        alo[0] = f2bf(a0[0]); alo[1] = f2bf(a0[1]); alo[2] = f2bf(a0[2]); alo[3] = f2bf(a0[3]);
        alo[4] = f2bf(a1[0]); alo[5] = f2bf(a1[1]); alo[6] = f2bf(a1[2]); alo[7] = f2bf(a1[3]);
        ahi[0] = f2bf(a2[0]); ahi[1] = f2bf(a2[1]); ahi[2] = f2bf(a2[2]); ahi[3] = f2bf(a2[3]);
        ahi[4] = f2bf(a3[0]); ahi[5] = f2bf(a3[1]); ahi[6] = f2bf(a3[2]); ahi[7] = f2bf(a3[3]);

        if (it + 1 < TPW) {            // prefetch A(it+1)
            const float* xp = xw + (size_t)((tile0 + it + 1) * RT + m16) * DIM;
            a0 = *(const f32x4*)(xp);      a1 = *(const f32x4*)(xp + 4);
            a2 = *(const f32x4*)(xp + 32); a3 = *(const f32x4*)(xp + 36);
        }

        // MFMA: acc[n][i] = y[4g+i][w*64 + n*16 + m16]
        f32x4 acc[4];
#pragma unroll
        for (int n = 0; n < 4; ++n) acc[n] = (f32x4){0.f, 0.f, 0.f, 0.f};
#pragma unroll
        for (int n = 0; n < 4; ++n)
            acc[n] = __builtin_amdgcn_mfma_f32_16x16x32_bf16(alo, bfr[n][0], acc[n], 0, 0, 0);
#pragma unroll
        for (int n = 0; n < 4; ++n)
            acc[n] = __builtin_amdgcn_mfma_f32_16x16x32_bf16(ahi, bfr[n][1], acc[n], 0, 0, 0);

        // scatter into pre-permuted bf16 y'(it)
#pragma unroll
        for (int n = 0; n < 4; ++n)
#pragma unroll
            for (int i = 0; i < 4; ++i)
                *(ushort*)(yc + (4 * g + i) * 2048 + jb[n]) = f2bf(acc[n][i]);

        // epilogue(it-1): row w from the other buffer
        if (it) {
            const char* yp = (const char*)ybuf[(it & 1) ^ 1] + w * 2048;
            float* orow = out + (size_t)((tile0 + it - 1) * RT + w) * DIM;
#pragma unroll
            for (int i = 0; i < 4; ++i) {
                const int e = ebase + i * 128;
                const uintx2 u = *(const uintx2*)(yp + e * 2);
                f32x4 v;
                v[0] = bflo2f(u[0]); v[1] = bfhi2f(u[0]);
                v[2] = bflo2f(u[1]); v[3] = bfhi2f(u[1]);
                *(f32x4*)(orow + e) = v;
            }
        }

        WAITL(); SBAR();               // scatter visible; epilogue reads done
    }

    // final epilogue: tile TPW-1
    {
        const char* yp = (const char*)ybuf[(TPW - 1) & 1] + w * 2048;
        float* orow = out + (size_t)((tile0 + TPW - 1) * RT + w) * DIM;
#pragma unroll
        for (int i = 0; i < 4; ++i) {
            const int e = ebase + i * 128;
            const uintx2 u = *(const uintx2*)(yp + e * 2);
            f32x4 v;
            v[0] = bflo2f(u[0]); v[1] = bfhi2f(u[0]);
            v[2] = bflo2f(u[1]); v[3] = bfhi2f(u[1]);
            *(f32x4*)(orow + e) = v;
        }
    }
}

// ---------------------------------------------------------------------------
extern "C" void kernel_launch(void* const* d_in, const int* in_sizes, int n_in,
                              void* d_out, int out_size, void* d_ws, size_t ws_size,
                              hipStream_t stream) {
    const float* x    = (const float*)d_in[0];   // [65536, 1024] f32
    const float* skew = (const float*)d_in[1];   // [16, 64, 64] f32
    const int*   perm = (const int*)d_in[2];     // [1024] i32/i64 (detected)
    float* out = (float*)d_out;

    // ws: [0,128KB) Btl bf16 lane-linear; [128KB,+4KB) inverse perm i32
    ushort* Btl  = (ushort*)d_ws;
    int*    pinv = (int*)((char*)d_ws + (size_t)NB * BLK * BLK * sizeof(ushort));

    expm_kernel<<<NB + 1, 512, 0, stream>>>(skew, Btl, perm, pinv);
    gsl_main_kernel<<<NWG, MAIN_THREADS, 0, stream>>>(x, Btl, pinv, out);
}